// Round 4
// baseline (81.772 us; speedup 1.0000x reference)
//
#include <hip/hip_runtime.h>

#define NN 32767   // n_nodes
#define NL 16384   // n_leaves
#define DD 1024    // D
#define LL 32      // num labels

typedef __attribute__((ext_vector_type(8))) short bf16x8;
typedef __attribute__((ext_vector_type(4))) float f32x4;

__device__ __forceinline__ short f2bf(float f) {
  union { float f; unsigned u; } x; x.f = f;
  unsigned r = x.u + 0x7FFFu + ((x.u >> 16) & 1u);  // RNE
  return (short)(r >> 16);
}

__device__ __forceinline__ bf16x8 cvt8(float4 a, float4 b) {
  bf16x8 r;
  r[0] = f2bf(a.x); r[1] = f2bf(a.y); r[2] = f2bf(a.z); r[3] = f2bf(a.w);
  r[4] = f2bf(b.x); r[5] = f2bf(b.y); r[6] = f2bf(b.z); r[7] = f2bf(b.w);
  return r;
}

// Pack W_pred (both K-halves, all 32 output cols) into bf16 MFMA B-fragment
// order: element idx = ((s*64 + lane)*4 + m)*8 + j, s=K/32 granule 0..31,
// m: 0=W1 cols0-15, 1=W1 cols16-31, 2=W2 cols0-15, 3=W2 cols16-31.
__global__ __launch_bounds__(256) void pack_kernel(const float* __restrict__ Wp,
                                                   short* __restrict__ Wpk) {
  int idx = blockIdx.x * 256 + threadIdx.x;   // grid 64 -> 16384 threads
  #pragma unroll
  for (int t = 0; t < 4; ++t, idx += 16384) {
    const int j = idx & 7, m = (idx >> 3) & 3, lane = (idx >> 5) & 63, s = idx >> 11;
    const int wrow = (lane & 15) + 16 * (m & 1);
    const int wcol = (m >> 1) * 1024 + s * 32 + (lane >> 4) * 8 + j;
    Wpk[idx] = f2bf(Wp[(size_t)wrow * (2 * DD) + wcol]);
  }
}

// E0 = hidden @ W1^T (stored) + per-block rowsum partial of E2 = hidden @ W2^T.
// 16 waves/block = 8 tiles x 2 K-halves. Plain global->VGPR loads; latency
// hidden by TLP (16 waves/CU). K-halves combined via LDS in epilogue.
__global__ __launch_bounds__(1024, 4) void gemm_kernel(
    const float* __restrict__ hidden, const short* __restrict__ Wpk,
    float* __restrict__ E0, float* __restrict__ gpartB) {
  __shared__ float cmb[8 * 1024];      // 32 KB K-half combine
  __shared__ float part2[8][LL];       // per-tile E2 partials
  const int tid = threadIdx.x;
  const int wid = tid >> 6, lane = tid & 63;
  const int wt = wid & 7, kh = wid >> 3;
  const int tile = blockIdx.x * 8 + wt;          // 0..2047
  const int mrow = lane & 15, g = lane >> 4;
  int grow = tile * 16 + mrow;
  if (grow > NN - 1) grow = NN - 1;              // clamp (dup row 32766)

  const float*  ap = hidden + (size_t)grow * DD + kh * 512 + g * 8;
  const bf16x8* wb = (const bf16x8*)Wpk + kh * 4096 + lane * 4;

  f32x4 acc0 = {0,0,0,0}, acc1 = {0,0,0,0}, acc2 = {0,0,0,0}, acc3 = {0,0,0,0};

  #pragma unroll
  for (int c = 0; c < 8; ++c) {
    float4 a0 = *(const float4*)(ap + c * 64);
    float4 a1 = *(const float4*)(ap + c * 64 + 4);
    float4 a2 = *(const float4*)(ap + c * 64 + 32);
    float4 a3 = *(const float4*)(ap + c * 64 + 36);
    const bf16x8* p = wb + c * 512;
    bf16x8 w0 = p[0],   w1 = p[1],   w2 = p[2],   w3 = p[3];
    bf16x8 x0 = p[256], x1 = p[257], x2 = p[258], x3 = p[259];
    bf16x8 af0 = cvt8(a0, a1);
    acc0 = __builtin_amdgcn_mfma_f32_16x16x32_bf16(af0, w0, acc0, 0, 0, 0);
    acc1 = __builtin_amdgcn_mfma_f32_16x16x32_bf16(af0, w1, acc1, 0, 0, 0);
    acc2 = __builtin_amdgcn_mfma_f32_16x16x32_bf16(af0, w2, acc2, 0, 0, 0);
    acc3 = __builtin_amdgcn_mfma_f32_16x16x32_bf16(af0, w3, acc3, 0, 0, 0);
    bf16x8 af1 = cvt8(a2, a3);
    acc0 = __builtin_amdgcn_mfma_f32_16x16x32_bf16(af1, x0, acc0, 0, 0, 0);
    acc1 = __builtin_amdgcn_mfma_f32_16x16x32_bf16(af1, x1, acc1, 0, 0, 0);
    acc2 = __builtin_amdgcn_mfma_f32_16x16x32_bf16(af1, x2, acc2, 0, 0, 0);
    acc3 = __builtin_amdgcn_mfma_f32_16x16x32_bf16(af1, x3, acc3, 0, 0, 0);
  }

  float* cl = cmb + wt * 1024 + lane * 16;
  if (kh == 1) {
    *(f32x4*)(cl)      = acc0;
    *(f32x4*)(cl + 4)  = acc1;
    *(f32x4*)(cl + 8)  = acc2;
    *(f32x4*)(cl + 12) = acc3;
  }
  __syncthreads();
  if (kh == 0) {
    acc0 += *(const f32x4*)(cl);
    acc1 += *(const f32x4*)(cl + 4);
    acc2 += *(const f32x4*)(cl + 8);
    acc3 += *(const f32x4*)(cl + 12);
    // E0 store: D layout col=lane&15, row=(lane>>4)*4+r
    #pragma unroll
    for (int r = 0; r < 4; ++r) {
      const int srow = tile * 16 + g * 4 + r;
      if (srow < NN) {
        E0[(size_t)srow * LL + mrow]      = acc0[r];
        E0[(size_t)srow * LL + mrow + 16] = acc1[r];
      }
    }
    // E2 rowsum (drop duplicated clamped row in last tile)
    if (tile == 2047 && g == 3) { acc2[3] = 0.f; acc3[3] = 0.f; }
    float s2 = acc2[0] + acc2[1] + acc2[2] + acc2[3];
    float s3 = acc3[0] + acc3[1] + acc3[2] + acc3[3];
    s2 += __shfl_xor(s2, 16, 64); s2 += __shfl_xor(s2, 32, 64);
    s3 += __shfl_xor(s3, 16, 64); s3 += __shfl_xor(s3, 32, 64);
    if (lane < 32) part2[wt][lane] = (lane < 16) ? s2 : s3;
  }
  __syncthreads();
  if (tid < LL) {
    float s = 0.f;
    #pragma unroll
    for (int q = 0; q < 8; ++q) s += part2[q][tid];
    gpartB[blockIdx.x * LL + tid] = s;
  }
}

__device__ __forceinline__ float lse32(const float4* tt, const float4* sv) {
  float m = -3.0e38f;
  float4 v[8];
  #pragma unroll
  for (int i = 0; i < 8; ++i) {
    float4 t = tt[i], s = sv[i], w;
    w.x = t.x + s.x; w.y = t.y + s.y; w.z = t.z + s.z; w.w = t.w + s.w;
    v[i] = w;
    m = fmaxf(m, fmaxf(fmaxf(w.x, w.y), fmaxf(w.z, w.w)));
  }
  float ss = 0.f;
  #pragma unroll
  for (int i = 0; i < 8; ++i) {
    ss += __expf(v[i].x - m) + __expf(v[i].y - m) +
          __expf(v[i].z - m) + __expf(v[i].w - m);
  }
  return m + __logf(ss);
}

// In-block cvec: cv[j] = b[j] + colsum(gpartB)/NN  (gpartB: 256x32)
__device__ __forceinline__ void compute_cvec(const float* __restrict__ gpartB,
                                             const float* __restrict__ bp,
                                             float* cv, float (*pr)[LL]) {
  const int tid = threadIdx.x;
  const int j = tid & 31, r = tid >> 5;   // needs 1024 threads
  float s = 0.f;
  #pragma unroll
  for (int q = 0; q < 8; ++q) s += gpartB[(size_t)(r + q * 32) * LL + j];
  pr[r][j] = s;
  __syncthreads();
  if (tid < LL) {
    float ss = 0.f;
    #pragma unroll
    for (int q = 0; q < 32; ++q) ss += pr[q][tid];
    cv[tid] = bp[tid] + ss * (1.0f / (float)NN);
  }
  __syncthreads();
}

// Five tree levels per launch (children of base_l+n are base_{l-1}+2n,2n+1).
// Block: 16 waves -> 16/8/4/2/1 nodes across 5 phases via LDS.
__global__ __launch_bounds__(1024) void tree_kernel(
    const float* __restrict__ E0, const float* __restrict__ gpartB,
    const float* __restrict__ bp, const float* __restrict__ trans,
    const float* __restrict__ src, float* __restrict__ dst,
    int base1, int leafmode) {
  __shared__ __align__(16) float cv[LL];
  __shared__ float pr[32][LL];
  __shared__ float l1[16][LL], l2[8][LL], l3[4][LL];
  compute_cvec(gpartB, bp, cv, pr);

  const int wid = threadIdx.x >> 6, lane = threadIdx.x & 63;
  const int j = lane & 31, half = lane >> 5;
  const int b = blockIdx.x, G = gridDim.x;
  float4 tt[8];
  #pragma unroll
  for (int i = 0; i < 8; ++i) tt[i] = *(const float4*)(trans + j * LL + i * 4);
  const float cj = cv[j];
  float4 sv[8];

  { // phase 1
    const int n = b * 16 + wid;
    const float* sp = src + (size_t)(2 * n + half) * LL;
    if (leafmode) {
      #pragma unroll
      for (int i = 0; i < 8; ++i) {
        float4 vv = *(const float4*)(sp + i * 4);
        float4 c4 = *(const float4*)(cv + i * 4);
        vv.x += c4.x; vv.y += c4.y; vv.z += c4.z; vv.w += c4.w;
        sv[i] = vv;
      }
    } else {
      #pragma unroll
      for (int i = 0; i < 8; ++i) sv[i] = *(const float4*)(sp + i * 4);
    }
    float lsum = lse32(tt, sv);
    float other = __shfl_xor(lsum, 32, 64);
    float o = E0[(size_t)(base1 + n) * LL + j] + cj + lsum + other;
    if (lane < 32) l1[wid][j] = o;
  }
  __syncthreads();
  const int base2 = base1 + G * 16;
  if (wid < 8) { // phase 2
    const float* sp = l1[2 * wid + half];
    #pragma unroll
    for (int i = 0; i < 8; ++i) sv[i] = *(const float4*)(sp + i * 4);
    float lsum = lse32(tt, sv);
    float other = __shfl_xor(lsum, 32, 64);
    float o = E0[(size_t)(base2 + b * 8 + wid) * LL + j] + cj + lsum + other;
    if (lane < 32) l2[wid][j] = o;
  }
  __syncthreads();
  const int base3 = base2 + G * 8;
  if (wid < 4) { // phase 3
    const float* sp = l2[2 * wid + half];
    #pragma unroll
    for (int i = 0; i < 8; ++i) sv[i] = *(const float4*)(sp + i * 4);
    float lsum = lse32(tt, sv);
    float other = __shfl_xor(lsum, 32, 64);
    float o = E0[(size_t)(base3 + b * 4 + wid) * LL + j] + cj + lsum + other;
    if (lane < 32) l3[wid][j] = o;
  }
  __syncthreads();
  const int base4 = base3 + G * 4;
  if (wid < 2) { // phase 4
    const float* sp = l3[2 * wid + half];
    #pragma unroll
    for (int i = 0; i < 8; ++i) sv[i] = *(const float4*)(sp + i * 4);
    float lsum = lse32(tt, sv);
    float other = __shfl_xor(lsum, 32, 64);
    float o = E0[(size_t)(base4 + b * 2 + wid) * LL + j] + cj + lsum + other;
    if (lane < 32) l1[wid][j] = o;
  }
  __syncthreads();
  const int base5 = base4 + G * 2;
  if (wid == 0) { // phase 5
    const float* sp = l1[half];
    #pragma unroll
    for (int i = 0; i < 8; ++i) sv[i] = *(const float4*)(sp + i * 4);
    float lsum = lse32(tt, sv);
    float other = __shfl_xor(lsum, 32, 64);
    float o = E0[(size_t)(base5 + b) * LL + j] + cj + lsum + other;
    if (lane < 32) dst[(size_t)b * LL + j] = o;
  }
}

// Widths 8,4,2,1 (nodes 32752..32766); writes root scores to out.
__global__ __launch_bounds__(1024) void tail_kernel(
    const float* __restrict__ E0, const float* __restrict__ gpartB,
    const float* __restrict__ bp, const float* __restrict__ trans,
    const float* __restrict__ S10, float* __restrict__ out) {
  __shared__ __align__(16) float cv[LL];
  __shared__ float pr[32][LL];
  __shared__ float t1[8][LL], t2[4][LL], t3[2][LL];
  compute_cvec(gpartB, bp, cv, pr);

  const int wid = threadIdx.x >> 6, lane = threadIdx.x & 63;
  const int j = lane & 31, half = lane >> 5;
  float4 tt[8];
  #pragma unroll
  for (int i = 0; i < 8; ++i) tt[i] = *(const float4*)(trans + j * LL + i * 4);
  const float cj = cv[j];
  float4 sv[8];

  if (wid < 8) { // width 8
    const float* sp = S10 + (size_t)(2 * wid + half) * LL;
    #pragma unroll
    for (int i = 0; i < 8; ++i) sv[i] = *(const float4*)(sp + i * 4);
    float lsum = lse32(tt, sv);
    float other = __shfl_xor(lsum, 32, 64);
    float o = E0[(size_t)(32752 + wid) * LL + j] + cj + lsum + other;
    if (lane < 32) t1[wid][j] = o;
  }
  __syncthreads();
  if (wid < 4) { // width 4
    const float* sp = t1[2 * wid + half];
    #pragma unroll
    for (int i = 0; i < 8; ++i) sv[i] = *(const float4*)(sp + i * 4);
    float lsum = lse32(tt, sv);
    float other = __shfl_xor(lsum, 32, 64);
    float o = E0[(size_t)(32760 + wid) * LL + j] + cj + lsum + other;
    if (lane < 32) t2[wid][j] = o;
  }
  __syncthreads();
  if (wid < 2) { // width 2
    const float* sp = t2[2 * wid + half];
    #pragma unroll
    for (int i = 0; i < 8; ++i) sv[i] = *(const float4*)(sp + i * 4);
    float lsum = lse32(tt, sv);
    float other = __shfl_xor(lsum, 32, 64);
    float o = E0[(size_t)(32764 + wid) * LL + j] + cj + lsum + other;
    if (lane < 32) t3[wid][j] = o;
  }
  __syncthreads();
  if (wid == 0) { // root = node 32766
    const float* sp = t3[half];
    #pragma unroll
    for (int i = 0; i < 8; ++i) sv[i] = *(const float4*)(sp + i * 4);
    float lsum = lse32(tt, sv);
    float other = __shfl_xor(lsum, 32, 64);
    float o = E0[(size_t)32766 * LL + j] + cj + lsum + other;
    if (lane < 32) out[j] = o;
  }
}

extern "C" void kernel_launch(void* const* d_in, const int* in_sizes, int n_in,
                              void* d_out, int out_size, void* d_ws, size_t ws_size,
                              hipStream_t stream) {
  const float* hidden = (const float*)d_in[0];
  const float* trans  = (const float*)d_in[1];
  const float* Wp     = (const float*)d_in[2];
  const float* bp     = (const float*)d_in[3];

  float* ws     = (float*)d_ws;
  float* E0     = ws;                               // NN*32 f32
  float* gpartB = E0 + (size_t)NN * LL;             // 256*32 f32
  float* S5     = gpartB + 256 * LL;                // 512*32 f32
  float* S10    = S5 + 512 * LL;                    // 16*32 f32
  short* Wpk    = (short*)(S10 + 16 * LL);          // 65536 bf16

  pack_kernel<<<64, 256, 0, stream>>>(Wp, Wpk);
  gemm_kernel<<<256, 1024, 0, stream>>>(hidden, Wpk, E0, gpartB);
  // widths 8192..512
  tree_kernel<<<512, 1024, 0, stream>>>(E0, gpartB, bp, trans, E0, S5, 16384, 1);
  // widths 256..16
  tree_kernel<<<16, 1024, 0, stream>>>(E0, gpartB, bp, trans, S5, S10, 32256, 0);
  // widths 8..1 + root write
  tail_kernel<<<1, 1024, 0, stream>>>(E0, gpartB, bp, trans, S10, (float*)d_out);
}